// Round 1
// baseline (151.567 us; speedup 1.0000x reference)
//
#include <hip/hip_runtime.h>
#include <math.h>

// Rotated 3D IoU loss, one thread per box pair, then block-reduce + atomicAdd.
// Replicates the JAX reference's exact edge-case semantics (see comments).

__global__ __launch_bounds__(256) void riou_loss_kernel(
    const float* __restrict__ pred, const float* __restrict__ tgt,
    const float* __restrict__ wgt, float* __restrict__ out, int n)
{
    int i = blockIdx.x * blockDim.x + threadIdx.x;
    float loss = 0.0f;
    if (i < n) {
        float p[7], q[7];
#pragma unroll
        for (int k = 0; k < 7; ++k) { p[k] = pred[7 * i + k]; q[k] = tgt[7 * i + k]; }

        // ---- decode_fcos_obb (loc = 0) ----
        float th1 = p[6];
        float w1 = p[0] + p[3], l1 = p[1] + p[4], h1 = p[2] + p[5];
        float ox1 = (p[3] - p[0]) * 0.5f, oy1 = (p[4] - p[1]) * 0.5f, oz1 = (p[5] - p[2]) * 0.5f;
        float cth1 = cosf(th1), sth1 = sinf(th1);
        float cx1 = ox1 * cth1 - oy1 * sth1;
        float cy1 = ox1 * sth1 + oy1 * cth1;

        float th2 = q[6];
        float w2 = q[0] + q[3], l2 = q[1] + q[4], h2 = q[2] + q[5];
        float ox2 = (q[3] - q[0]) * 0.5f, oy2 = (q[4] - q[1]) * 0.5f, oz2 = (q[5] - q[2]) * 0.5f;
        float cth2 = cosf(th2), sth2 = sinf(th2);
        float cx2 = ox2 * cth2 - oy2 * sth2;
        float cy2 = ox2 * sth2 + oy2 * cth2;

        // ---- box2corners: signs (+,+),(-,+),(-,-),(+,-) scaled by w/2, l/2 ----
        const float sxk[4] = {0.5f, -0.5f, -0.5f, 0.5f};
        const float syk[4] = {0.5f, 0.5f, -0.5f, -0.5f};
        float c1x[4], c1y[4], c2x[4], c2y[4];
#pragma unroll
        for (int k = 0; k < 4; ++k) {
            float xa = sxk[k] * w1, ya = syk[k] * l1;
            c1x[k] = xa * cth1 - ya * sth1 + cx1;
            c1y[k] = xa * sth1 + ya * cth1 + cy1;
            float xb = sxk[k] * w2, yb = syk[k] * l2;
            c2x[k] = xb * cth2 - yb * sth2 + cx2;
            c2y[k] = xb * sth2 + yb * cth2 + cy2;
        }

        // ---- collect valid polygon vertices (compacted, original order kept) ----
        float vx[24], vy[24];
        int nv = 0;
        float sumx = 0.0f, sumy = 0.0f;

        // box1 corners inside box2 (ref: a=c2[0], b=c2[1], d=c2[3], tol=1e-6)
        {
            float ax = c2x[0], ay = c2y[0];
            float abx = c2x[1] - ax, aby = c2y[1] - ay;
            float adx = c2x[3] - ax, ady = c2y[3] - ay;
            float ab2 = abx * abx + aby * aby, ad2 = adx * adx + ady * ady;
#pragma unroll
            for (int k = 0; k < 4; ++k) {
                float amx = c1x[k] - ax, amy = c1y[k] - ay;
                float pab = (abx * amx + aby * amy) / ab2;
                float pad = (adx * amx + ady * amy) / ad2;
                const float tol = 1e-6f;
                if (pab > -tol && pab < 1.0f + tol && pad > -tol && pad < 1.0f + tol) {
                    vx[nv] = c1x[k]; vy[nv] = c1y[k];
                    sumx += c1x[k]; sumy += c1y[k]; ++nv;
                }
            }
        }
        // box2 corners inside box1
        {
            float ax = c1x[0], ay = c1y[0];
            float abx = c1x[1] - ax, aby = c1y[1] - ay;
            float adx = c1x[3] - ax, ady = c1y[3] - ay;
            float ab2 = abx * abx + aby * aby, ad2 = adx * adx + ady * ady;
#pragma unroll
            for (int k = 0; k < 4; ++k) {
                float amx = c2x[k] - ax, amy = c2y[k] - ay;
                float pab = (abx * amx + aby * amy) / ab2;
                float pad = (adx * amx + ady * amy) / ad2;
                const float tol = 1e-6f;
                if (pab > -tol && pab < 1.0f + tol && pad > -tol && pad < 1.0f + tol) {
                    vx[nv] = c2x[k]; vy[nv] = c2y[k];
                    sumx += c2x[k]; sumy += c2y[k]; ++nv;
                }
            }
        }
        // 16 edge-edge intersections. Mask uses t=den_t/num (num!=0 guard);
        // the POINT uses t2=den_t/(num+1e-8) exactly as the reference.
#pragma unroll
        for (int e1 = 0; e1 < 4; ++e1) {
            float x1 = c1x[e1], y1 = c1y[e1];
            float x2 = c1x[(e1 + 1) & 3], y2 = c1y[(e1 + 1) & 3];
#pragma unroll
            for (int e2 = 0; e2 < 4; ++e2) {
                float x3 = c2x[e2], y3 = c2y[e2];
                float x4 = c2x[(e2 + 1) & 3], y4 = c2y[(e2 + 1) & 3];
                float num   = (y4 - y3) * (x2 - x1) - (x4 - x3) * (y2 - y1);
                float den_t = (x4 - x3) * (y1 - y3) - (y4 - y3) * (x1 - x3);
                float den_u = (x2 - x1) * (y1 - y3) - (y2 - y1) * (x1 - x3);
                float tt, uu;
                if (num == 0.0f) { tt = -1.0f; uu = -1.0f; }
                else             { tt = den_t / num; uu = -den_u / num; }
                if (tt > 0.0f && tt < 1.0f && uu > 0.0f && uu < 1.0f) {
                    float t2 = den_t / (num + 1e-8f);
                    float px = x1 + t2 * (x2 - x1);
                    float py = y1 + t2 * (y2 - y1);
                    vx[nv] = px; vy[nv] = py;
                    sumx += px; sumy += py; ++nv;
                }
            }
        }

        // ---- sorted_polygon_area ----
        float inter = 0.0f;
        if (nv > 0) {
            float mx = sumx / (float)nv, my = sumy / (float)nv;  // ref: /max(nv,1)
            float ang[24];
            for (int k = 0; k < nv; ++k) {
                vx[k] -= mx; vy[k] -= my;
                ang[k] = atan2f(vy[k], vx[k]);
            }
            // stable insertion sort by angle (matches stable jnp.argsort on ties)
            for (int a = 1; a < nv; ++a) {
                float ka = ang[a], kx = vx[a], ky = vy[a];
                int b = a - 1;
                while (b >= 0 && ang[b] > ka) {
                    ang[b + 1] = ang[b]; vx[b + 1] = vx[b]; vy[b + 1] = vy[b];
                    --b;
                }
                ang[b + 1] = ka; vx[b + 1] = kx; vy[b + 1] = ky;
            }
            // cyclic shoelace over the nv valid sorted vertices
            // (ref pads with first sorted vertex -> identical cyclic sum)
            float cs = 0.0f;
            for (int k = 0; k < nv; ++k) {
                int k2 = (k + 1 == nv) ? 0 : (k + 1);
                cs += vx[k] * vy[k2] - vy[k] * vx[k2];
            }
            inter = 0.5f * fabsf(cs);
        }

        // ---- cal_iou_3d + loss ----
        float area1 = w1 * l1, area2 = w2 * l2;
        float u2 = area1 + area2 - inter;
        float iou2d = inter / u2;
        float zmax1 = oz1 + h1 * 0.5f, zmin1 = oz1 - h1 * 0.5f;
        float zmax2 = oz2 + h2 * 0.5f, zmin2 = oz2 - h2 * 0.5f;
        float zo = fminf(zmax1, zmax2) - fmaxf(zmin1, zmin2);
        zo = fmaxf(zo, 0.0f);
        float inter3d = iou2d * u2 * zo;
        float vol1 = area1 * h1, vol2 = area2 * h2;
        float u3d = vol1 + vol2 - inter3d;
        float iou3dv = inter3d / u3d;       // cal_iou_3d's ious
        float vol_inter = iou3dv * u3d;     // rotated_iou_loss: ious*unions
        float iouf = (vol_inter + 1.0f) / (u3d + 1.0f);
        loss = -logf(iouf) * wgt[i];
    }

    // ---- block reduction -> one atomicAdd per block ----
#pragma unroll
    for (int off = 32; off > 0; off >>= 1)
        loss += __shfl_down(loss, off, 64);
    __shared__ float wsum[4];
    int lane = threadIdx.x & 63, wid = threadIdx.x >> 6;
    if (lane == 0) wsum[wid] = loss;
    __syncthreads();
    if (threadIdx.x == 0) {
        float s = wsum[0] + wsum[1] + wsum[2] + wsum[3];
        atomicAdd(out, s);
    }
}

extern "C" void kernel_launch(void* const* d_in, const int* in_sizes, int n_in,
                              void* d_out, int out_size, void* d_ws, size_t ws_size,
                              hipStream_t stream) {
    const float* pred = (const float*)d_in[0];
    const float* tgt  = (const float*)d_in[1];
    const float* wgt  = (const float*)d_in[2];
    float* out = (float*)d_out;
    int n = in_sizes[2];  // weight has one entry per element

    hipMemsetAsync(out, 0, sizeof(float), stream);  // capture-legal
    int block = 256;
    int grid = (n + block - 1) / block;
    riou_loss_kernel<<<grid, block, 0, stream>>>(pred, tgt, wgt, out, n);
}

// Round 2
// 96.942 us; speedup vs baseline: 1.5635x; 1.5635x over previous
//
#include <hip/hip_runtime.h>
#include <math.h>

// Rotated 3D IoU loss. Fully register-resident, branch-free per-thread path:
//  - 24 fixed candidate-vertex slots (4+4 corners, 16 edge intersections)
//  - Batcher odd-even merge sorting network (constexpr-generated, constant
//    indices -> no scratch, no divergence) over (pseudo-angle, x, y) triples
//  - pseudo-angle (diamond angle) is strictly monotone in atan2 -> same order
//  - reference's "pad with first sorted vertex" via k<nv selects (constant k)
// Then block shuffle-reduce + one atomicAdd.

struct Net { int a[256]; int b[256]; int n; };

static constexpr Net make_net() {
    Net r{};
    r.n = 0;
    const int N = 32, LIM = 24;  // sort conceptual 32, slots >=24 are +inf (pruned)
    for (int p = 1; p < N; p *= 2)
        for (int k = p; k >= 1; k /= 2)
            for (int j = k % p; j <= N - 1 - k; j += 2 * k)
                for (int i = 0; i < k; ++i) {
                    if (i > N - j - k - 1) break;
                    int lo = i + j, hi = i + j + k;
                    if ((lo / (p * 2)) == (hi / (p * 2)) && hi < LIM) {
                        r.a[r.n] = lo; r.b[r.n] = hi; ++r.n;
                    }
                }
    return r;
}

__device__ __forceinline__ float pseudo_angle(float x, float y) {
    // monotone bijection of atan2(y,x) from (-pi,pi] onto [-2,2]
    float d = y / fmaxf(fabsf(x) + fabsf(y), 1e-38f);
    return (x >= 0.0f) ? d : (copysignf(2.0f, y) - d);
}

__global__ __launch_bounds__(256) void riou_loss_kernel(
    const float* __restrict__ pred, const float* __restrict__ tgt,
    const float* __restrict__ wgt, float* __restrict__ out, int n)
{
    int i = blockIdx.x * blockDim.x + threadIdx.x;
    float loss = 0.0f;
    if (i < n) {
        float p[7], q[7];
#pragma unroll
        for (int k = 0; k < 7; ++k) { p[k] = pred[7 * i + k]; q[k] = tgt[7 * i + k]; }

        // ---- decode_fcos_obb (loc = 0) ----
        float th1 = p[6];
        float w1 = p[0] + p[3], l1 = p[1] + p[4], h1 = p[2] + p[5];
        float ox1 = (p[3] - p[0]) * 0.5f, oy1 = (p[4] - p[1]) * 0.5f, oz1 = (p[5] - p[2]) * 0.5f;
        float sth1, cth1; sincosf(th1, &sth1, &cth1);
        float cx1 = ox1 * cth1 - oy1 * sth1;
        float cy1 = ox1 * sth1 + oy1 * cth1;

        float th2 = q[6];
        float w2 = q[0] + q[3], l2 = q[1] + q[4], h2 = q[2] + q[5];
        float ox2 = (q[3] - q[0]) * 0.5f, oy2 = (q[4] - q[1]) * 0.5f, oz2 = (q[5] - q[2]) * 0.5f;
        float sth2, cth2; sincosf(th2, &sth2, &cth2);
        float cx2 = ox2 * cth2 - oy2 * sth2;
        float cy2 = ox2 * sth2 + oy2 * cth2;

        // ---- box2corners: signs (+,+),(-,+),(-,-),(+,-) scaled by w/2, l/2 ----
        const float sxk[4] = {0.5f, -0.5f, -0.5f, 0.5f};
        const float syk[4] = {0.5f, 0.5f, -0.5f, -0.5f};
        float c1x[4], c1y[4], c2x[4], c2y[4];
#pragma unroll
        for (int k = 0; k < 4; ++k) {
            float xa = sxk[k] * w1, ya = syk[k] * l1;
            c1x[k] = xa * cth1 - ya * sth1 + cx1;
            c1y[k] = xa * sth1 + ya * cth1 + cy1;
            float xb = sxk[k] * w2, yb = syk[k] * l2;
            c2x[k] = xb * cth2 - yb * sth2 + cx2;
            c2y[k] = xb * sth2 + yb * cth2 + cy2;
        }

        // ---- 24 fixed candidate slots ----
        float vx[24], vy[24];
        bool valid[24];
        float sumx = 0.0f, sumy = 0.0f;
        int nv = 0;

        // slots 0..3: box1 corners inside box2 (ref: a=c2[0], b=c2[1], d=c2[3])
        {
            float ax = c2x[0], ay = c2y[0];
            float abx = c2x[1] - ax, aby = c2y[1] - ay;
            float adx = c2x[3] - ax, ady = c2y[3] - ay;
            float rab = 1.0f / (abx * abx + aby * aby);
            float rad = 1.0f / (adx * adx + ady * ady);
#pragma unroll
            for (int k = 0; k < 4; ++k) {
                float amx = c1x[k] - ax, amy = c1y[k] - ay;
                float pab = (abx * amx + aby * amy) * rab;
                float pad = (adx * amx + ady * amy) * rad;
                const float tol = 1e-6f;
                bool m = (pab > -tol) & (pab < 1.0f + tol) & (pad > -tol) & (pad < 1.0f + tol);
                vx[k] = c1x[k]; vy[k] = c1y[k]; valid[k] = m;
                sumx += m ? c1x[k] : 0.0f; sumy += m ? c1y[k] : 0.0f; nv += m ? 1 : 0;
            }
        }
        // slots 4..7: box2 corners inside box1
        {
            float ax = c1x[0], ay = c1y[0];
            float abx = c1x[1] - ax, aby = c1y[1] - ay;
            float adx = c1x[3] - ax, ady = c1y[3] - ay;
            float rab = 1.0f / (abx * abx + aby * aby);
            float rad = 1.0f / (adx * adx + ady * ady);
#pragma unroll
            for (int k = 0; k < 4; ++k) {
                float amx = c2x[k] - ax, amy = c2y[k] - ay;
                float pab = (abx * amx + aby * amy) * rab;
                float pad = (adx * amx + ady * amy) * rad;
                const float tol = 1e-6f;
                bool m = (pab > -tol) & (pab < 1.0f + tol) & (pad > -tol) & (pad < 1.0f + tol);
                vx[4 + k] = c2x[k]; vy[4 + k] = c2y[k]; valid[4 + k] = m;
                sumx += m ? c2x[k] : 0.0f; sumy += m ? c2y[k] : 0.0f; nv += m ? 1 : 0;
            }
        }
        // slots 8..23: edge-edge intersections (e1 outer, e2 inner, like ref)
#pragma unroll
        for (int e1 = 0; e1 < 4; ++e1) {
            float x1 = c1x[e1], y1 = c1y[e1];
            float x2 = c1x[(e1 + 1) & 3], y2 = c1y[(e1 + 1) & 3];
#pragma unroll
            for (int e2 = 0; e2 < 4; ++e2) {
                float x3 = c2x[e2], y3 = c2y[e2];
                float x4 = c2x[(e2 + 1) & 3], y4 = c2y[(e2 + 1) & 3];
                float num   = (y4 - y3) * (x2 - x1) - (x4 - x3) * (y2 - y1);
                float den_t = (x4 - x3) * (y1 - y3) - (y4 - y3) * (x1 - x3);
                float den_u = (x2 - x1) * (y1 - y3) - (y2 - y1) * (x1 - x3);
                // num==0 -> r=inf/nan -> tt/uu inf or nan -> mask false (matches ref's -1)
                float r  = 1.0f / num;
                float tt = den_t * r;
                float uu = -den_u * r;
                bool m = (tt > 0.0f) & (tt < 1.0f) & (uu > 0.0f) & (uu < 1.0f);
                float t2 = den_t / (num + 1e-8f);   // ref uses EPS denominator for the POINT
                float px = x1 + t2 * (x2 - x1);
                float py = y1 + t2 * (y2 - y1);
                int s = 8 + e1 * 4 + e2;
                vx[s] = px; vy[s] = py; valid[s] = m;
                sumx += m ? px : 0.0f; sumy += m ? py : 0.0f; nv += m ? 1 : 0;
            }
        }

        // ---- centroid-relative coords + pseudo-angle (invalid -> 1e6, like ref) ----
        float inv_nv = 1.0f / fmaxf((float)nv, 1.0f);
        float mx = sumx * inv_nv, my = sumy * inv_nv;
        float ang[24];
#pragma unroll
        for (int k = 0; k < 24; ++k) {
            vx[k] -= mx; vy[k] -= my;
            ang[k] = valid[k] ? pseudo_angle(vx[k], vy[k]) : 1e6f;
        }

        // ---- Batcher sorting network, constant indices ----
        constexpr Net NET = make_net();
#pragma unroll
        for (int t = 0; t < NET.n; ++t) {
            const int a = NET.a[t], b = NET.b[t];
            bool sw = ang[a] > ang[b];
            float ta = ang[a], tb = ang[b];
            ang[a] = sw ? tb : ta;  ang[b] = sw ? ta : tb;
            float xa = vx[a], xb = vx[b];
            vx[a] = sw ? xb : xa;   vx[b] = sw ? xa : xb;
            float ya = vy[a], yb = vy[b];
            vy[a] = sw ? yb : ya;   vy[b] = sw ? ya : yb;
        }

        // ---- ref padding: slots k>=nv become first sorted vertex ----
        float v0x = vx[0], v0y = vy[0];
#pragma unroll
        for (int k = 1; k < 24; ++k) {
            bool pad = (k >= nv);
            vx[k] = pad ? v0x : vx[k];
            vy[k] = pad ? v0y : vy[k];
        }
        // cyclic shoelace over all 24 (pad slots contribute 0 / the wrap term)
        float cs = 0.0f;
#pragma unroll
        for (int k = 0; k < 24; ++k) {
            int k2 = (k + 1) & 31; k2 = (k2 == 24) ? 0 : k2;  // (k+1)%24, constant
            cs += vx[k] * vy[k2] - vy[k] * vx[k2];
        }
        float inter = 0.5f * fabsf(cs);

        // ---- cal_iou_3d + loss ----
        float area1 = w1 * l1, area2 = w2 * l2;
        float u2 = area1 + area2 - inter;
        float iou2d = inter / u2;
        float zmax1 = oz1 + h1 * 0.5f, zmin1 = oz1 - h1 * 0.5f;
        float zmax2 = oz2 + h2 * 0.5f, zmin2 = oz2 - h2 * 0.5f;
        float zo = fmaxf(fminf(zmax1, zmax2) - fmaxf(zmin1, zmin2), 0.0f);
        float inter3d = iou2d * u2 * zo;
        float vol1 = area1 * h1, vol2 = area2 * h2;
        float u3d = vol1 + vol2 - inter3d;
        float iou3dv = inter3d / u3d;
        float vol_inter = iou3dv * u3d;
        float iouf = (vol_inter + 1.0f) / (u3d + 1.0f);
        loss = -logf(iouf) * wgt[i];
    }

    // ---- block reduction -> one atomicAdd per block ----
#pragma unroll
    for (int off = 32; off > 0; off >>= 1)
        loss += __shfl_down(loss, off, 64);
    __shared__ float wsum[4];
    int lane = threadIdx.x & 63, wid = threadIdx.x >> 6;
    if (lane == 0) wsum[wid] = loss;
    __syncthreads();
    if (threadIdx.x == 0) {
        float s = wsum[0] + wsum[1] + wsum[2] + wsum[3];
        atomicAdd(out, s);
    }
}

extern "C" void kernel_launch(void* const* d_in, const int* in_sizes, int n_in,
                              void* d_out, int out_size, void* d_ws, size_t ws_size,
                              hipStream_t stream) {
    const float* pred = (const float*)d_in[0];
    const float* tgt  = (const float*)d_in[1];
    const float* wgt  = (const float*)d_in[2];
    float* out = (float*)d_out;
    int n = in_sizes[2];

    hipMemsetAsync(out, 0, sizeof(float), stream);
    int block = 256;
    int grid = (n + block - 1) / block;
    riou_loss_kernel<<<grid, block, 0, stream>>>(pred, tgt, wgt, out, n);
}

// Round 3
// 96.667 us; speedup vs baseline: 1.5679x; 1.0029x over previous
//
#include <hip/hip_runtime.h>
#include <math.h>

// Rotated 3D IoU loss. Fully register-resident, branch-free per-thread path.
// Round-3 fix: the Batcher network is applied via TEMPLATE RECURSION so that
// every vx/vy/ang index is a compile-time constant when SROA runs -> arrays
// promote to VGPRs (round 2's #pragma unroll left them in scratch: VGPR=56,
// WRITE_SIZE=30.5MB = 128B/thread spill traffic).

struct Net { int a[256]; int b[256]; int n; };

static constexpr Net make_net() {
    Net r{};
    r.n = 0;
    const int N = 32, LIM = 24;  // conceptual 32-sort; slots >=24 are +inf (pruned)
    for (int p = 1; p < N; p *= 2)
        for (int k = p; k >= 1; k /= 2)
            for (int j = k % p; j <= N - 1 - k; j += 2 * k)
                for (int i = 0; i < k; ++i) {
                    if (i > N - j - k - 1) break;
                    int lo = i + j, hi = i + j + k;
                    if ((lo / (p * 2)) == (hi / (p * 2)) && hi < LIM) {
                        r.a[r.n] = lo; r.b[r.n] = hi; ++r.n;
                    }
                }
    return r;
}

constexpr Net NET = make_net();

template <int T, int NTOT>
struct NetApply {
    __device__ static __forceinline__ void run(float (&ang)[24], float (&vx)[24], float (&vy)[24]) {
        constexpr int a = NET.a[T];
        constexpr int b = NET.b[T];
        bool sw = ang[a] > ang[b];
        float ta = ang[a], tb = ang[b];
        ang[a] = sw ? tb : ta;  ang[b] = sw ? ta : tb;
        float xa = vx[a], xb = vx[b];
        vx[a] = sw ? xb : xa;   vx[b] = sw ? xa : xb;
        float ya = vy[a], yb = vy[b];
        vy[a] = sw ? yb : ya;   vy[b] = sw ? ya : yb;
        NetApply<T + 1, NTOT>::run(ang, vx, vy);
    }
};
template <int NTOT>
struct NetApply<NTOT, NTOT> {
    __device__ static __forceinline__ void run(float (&)[24], float (&)[24], float (&)[24]) {}
};

__device__ __forceinline__ float pseudo_angle(float x, float y) {
    // monotone bijection of atan2(y,x) from (-pi,pi] onto [-2,2]
    float d = y / fmaxf(fabsf(x) + fabsf(y), 1e-38f);
    return (x >= 0.0f) ? d : (copysignf(2.0f, y) - d);
}

__global__ __launch_bounds__(256) void riou_loss_kernel(
    const float* __restrict__ pred, const float* __restrict__ tgt,
    const float* __restrict__ wgt, float* __restrict__ out, int n)
{
    int i = blockIdx.x * blockDim.x + threadIdx.x;
    float loss = 0.0f;
    if (i < n) {
        float p[7], q[7];
#pragma unroll
        for (int k = 0; k < 7; ++k) { p[k] = pred[7 * i + k]; q[k] = tgt[7 * i + k]; }

        // ---- decode_fcos_obb (loc = 0) ----
        float th1 = p[6];
        float w1 = p[0] + p[3], l1 = p[1] + p[4], h1 = p[2] + p[5];
        float ox1 = (p[3] - p[0]) * 0.5f, oy1 = (p[4] - p[1]) * 0.5f, oz1 = (p[5] - p[2]) * 0.5f;
        float sth1, cth1; sincosf(th1, &sth1, &cth1);
        float cx1 = ox1 * cth1 - oy1 * sth1;
        float cy1 = ox1 * sth1 + oy1 * cth1;

        float th2 = q[6];
        float w2 = q[0] + q[3], l2 = q[1] + q[4], h2 = q[2] + q[5];
        float ox2 = (q[3] - q[0]) * 0.5f, oy2 = (q[4] - q[1]) * 0.5f, oz2 = (q[5] - q[2]) * 0.5f;
        float sth2, cth2; sincosf(th2, &sth2, &cth2);
        float cx2 = ox2 * cth2 - oy2 * sth2;
        float cy2 = ox2 * sth2 + oy2 * cth2;

        // ---- box2corners: signs (+,+),(-,+),(-,-),(+,-) scaled by w/2, l/2 ----
        const float sxk[4] = {0.5f, -0.5f, -0.5f, 0.5f};
        const float syk[4] = {0.5f, 0.5f, -0.5f, -0.5f};
        float c1x[4], c1y[4], c2x[4], c2y[4];
#pragma unroll
        for (int k = 0; k < 4; ++k) {
            float xa = sxk[k] * w1, ya = syk[k] * l1;
            c1x[k] = xa * cth1 - ya * sth1 + cx1;
            c1y[k] = xa * sth1 + ya * cth1 + cy1;
            float xb = sxk[k] * w2, yb = syk[k] * l2;
            c2x[k] = xb * cth2 - yb * sth2 + cx2;
            c2y[k] = xb * sth2 + yb * cth2 + cy2;
        }

        // ---- 24 fixed candidate slots ----
        float vx[24], vy[24];
        bool valid[24];
        float sumx = 0.0f, sumy = 0.0f;
        int nv = 0;

        // slots 0..3: box1 corners inside box2 (ref: a=c2[0], b=c2[1], d=c2[3])
        {
            float ax = c2x[0], ay = c2y[0];
            float abx = c2x[1] - ax, aby = c2y[1] - ay;
            float adx = c2x[3] - ax, ady = c2y[3] - ay;
            float rab = 1.0f / (abx * abx + aby * aby);
            float rad = 1.0f / (adx * adx + ady * ady);
#pragma unroll
            for (int k = 0; k < 4; ++k) {
                float amx = c1x[k] - ax, amy = c1y[k] - ay;
                float pab = (abx * amx + aby * amy) * rab;
                float pad = (adx * amx + ady * amy) * rad;
                const float tol = 1e-6f;
                bool m = (pab > -tol) & (pab < 1.0f + tol) & (pad > -tol) & (pad < 1.0f + tol);
                vx[k] = c1x[k]; vy[k] = c1y[k]; valid[k] = m;
                sumx += m ? c1x[k] : 0.0f; sumy += m ? c1y[k] : 0.0f; nv += m ? 1 : 0;
            }
        }
        // slots 4..7: box2 corners inside box1
        {
            float ax = c1x[0], ay = c1y[0];
            float abx = c1x[1] - ax, aby = c1y[1] - ay;
            float adx = c1x[3] - ax, ady = c1y[3] - ay;
            float rab = 1.0f / (abx * abx + aby * aby);
            float rad = 1.0f / (adx * adx + ady * ady);
#pragma unroll
            for (int k = 0; k < 4; ++k) {
                float amx = c2x[k] - ax, amy = c2y[k] - ay;
                float pab = (abx * amx + aby * amy) * rab;
                float pad = (adx * amx + ady * amy) * rad;
                const float tol = 1e-6f;
                bool m = (pab > -tol) & (pab < 1.0f + tol) & (pad > -tol) & (pad < 1.0f + tol);
                vx[4 + k] = c2x[k]; vy[4 + k] = c2y[k]; valid[4 + k] = m;
                sumx += m ? c2x[k] : 0.0f; sumy += m ? c2y[k] : 0.0f; nv += m ? 1 : 0;
            }
        }
        // slots 8..23: edge-edge intersections
#pragma unroll
        for (int e1 = 0; e1 < 4; ++e1) {
            float x1 = c1x[e1], y1 = c1y[e1];
            float x2 = c1x[(e1 + 1) & 3], y2 = c1y[(e1 + 1) & 3];
#pragma unroll
            for (int e2 = 0; e2 < 4; ++e2) {
                float x3 = c2x[e2], y3 = c2y[e2];
                float x4 = c2x[(e2 + 1) & 3], y4 = c2y[(e2 + 1) & 3];
                float num   = (y4 - y3) * (x2 - x1) - (x4 - x3) * (y2 - y1);
                float den_t = (x4 - x3) * (y1 - y3) - (y4 - y3) * (x1 - x3);
                float den_u = (x2 - x1) * (y1 - y3) - (y2 - y1) * (x1 - x3);
                // num==0 -> r=inf/nan -> tt/uu inf or nan -> mask false (matches ref's -1)
                float r  = 1.0f / num;
                float tt = den_t * r;
                float uu = -den_u * r;
                bool m = (tt > 0.0f) & (tt < 1.0f) & (uu > 0.0f) & (uu < 1.0f);
                float t2 = den_t / (num + 1e-8f);   // ref uses EPS denominator for the POINT
                float px = x1 + t2 * (x2 - x1);
                float py = y1 + t2 * (y2 - y1);
                int s = 8 + e1 * 4 + e2;            // constant after unroll of constant-trip loops
                vx[s] = px; vy[s] = py; valid[s] = m;
                sumx += m ? px : 0.0f; sumy += m ? py : 0.0f; nv += m ? 1 : 0;
            }
        }

        // ---- centroid-relative coords + pseudo-angle (invalid -> 1e6, like ref) ----
        float inv_nv = 1.0f / fmaxf((float)nv, 1.0f);
        float mx = sumx * inv_nv, my = sumy * inv_nv;
        float ang[24];
#pragma unroll
        for (int k = 0; k < 24; ++k) {
            vx[k] -= mx; vy[k] -= my;
            ang[k] = valid[k] ? pseudo_angle(vx[k], vy[k]) : 1e6f;
        }

        // ---- Batcher sorting network, template-recursive (constant indices) ----
        NetApply<0, NET.n>::run(ang, vx, vy);

        // ---- ref padding: slots k>=nv become first sorted vertex ----
        float v0x = vx[0], v0y = vy[0];
#pragma unroll
        for (int k = 1; k < 24; ++k) {
            bool pad = (k >= nv);
            vx[k] = pad ? v0x : vx[k];
            vy[k] = pad ? v0y : vy[k];
        }
        // cyclic shoelace over all 24 (pad slots contribute 0 / the wrap term)
        float cs = 0.0f;
#pragma unroll
        for (int k = 0; k < 24; ++k) {
            int k2 = (k + 1 == 24) ? 0 : (k + 1);
            cs += vx[k] * vy[k2] - vy[k] * vx[k2];
        }
        float inter = 0.5f * fabsf(cs);

        // ---- cal_iou_3d + loss ----
        float area1 = w1 * l1, area2 = w2 * l2;
        float u2 = area1 + area2 - inter;
        float iou2d = inter / u2;
        float zmax1 = oz1 + h1 * 0.5f, zmin1 = oz1 - h1 * 0.5f;
        float zmax2 = oz2 + h2 * 0.5f, zmin2 = oz2 - h2 * 0.5f;
        float zo = fmaxf(fminf(zmax1, zmax2) - fmaxf(zmin1, zmin2), 0.0f);
        float inter3d = iou2d * u2 * zo;
        float vol1 = area1 * h1, vol2 = area2 * h2;
        float u3d = vol1 + vol2 - inter3d;
        float iou3dv = inter3d / u3d;
        float vol_inter = iou3dv * u3d;
        float iouf = (vol_inter + 1.0f) / (u3d + 1.0f);
        loss = -logf(iouf) * wgt[i];
    }

    // ---- block reduction -> one atomicAdd per block ----
#pragma unroll
    for (int off = 32; off > 0; off >>= 1)
        loss += __shfl_down(loss, off, 64);
    __shared__ float wsum[4];
    int lane = threadIdx.x & 63, wid = threadIdx.x >> 6;
    if (lane == 0) wsum[wid] = loss;
    __syncthreads();
    if (threadIdx.x == 0) {
        float s = wsum[0] + wsum[1] + wsum[2] + wsum[3];
        atomicAdd(out, s);
    }
}

extern "C" void kernel_launch(void* const* d_in, const int* in_sizes, int n_in,
                              void* d_out, int out_size, void* d_ws, size_t ws_size,
                              hipStream_t stream) {
    const float* pred = (const float*)d_in[0];
    const float* tgt  = (const float*)d_in[1];
    const float* wgt  = (const float*)d_in[2];
    float* out = (float*)d_out;
    int n = in_sizes[2];

    hipMemsetAsync(out, 0, sizeof(float), stream);
    int block = 256;
    int grid = (n + block - 1) / block;
    riou_loss_kernel<<<grid, block, 0, stream>>>(pred, tgt, wgt, out, n);
}

// Round 4
// 92.121 us; speedup vs baseline: 1.6453x; 1.0493x over previous
//
#include <hip/hip_runtime.h>
#include <math.h>

// Rotated 3D IoU loss — round 4: ZERO local arrays (all named scalars via
// token-pasted macros) so nothing can fall to scratch. 16-element candidate
// list (8 corners + first-2-valid crossings per box1 edge; a convex quad is
// crossed <=2x per line) sorted by pseudo-angle with a literal-index
// odd-even transposition network (16 rounds x ~8 CEs). Fast-math:
// v_rcp_f32 for divisions, __sinf/__cosf/__logf (threshold is 2% of sum).

#define RCP(x) __builtin_amdgcn_rcpf(x)

__global__ __launch_bounds__(256) void riou_loss_kernel(
    const float* __restrict__ pred, const float* __restrict__ tgt,
    const float* __restrict__ wgt, float* __restrict__ out, int n)
{
    int i = blockIdx.x * blockDim.x + threadIdx.x;
    float loss = 0.0f;
    if (i < n) {
        const float* pp = pred + 7 * i;
        const float* qq = tgt + 7 * i;
        float p0 = pp[0], p1 = pp[1], p2 = pp[2], p3 = pp[3], p4 = pp[4], p5 = pp[5], p6 = pp[6];
        float q0 = qq[0], q1 = qq[1], q2 = qq[2], q3 = qq[3], q4 = qq[4], q5 = qq[5], q6 = qq[6];

        // ---- decode_fcos_obb (loc = 0) ----
        float w1 = p0 + p3, l1 = p1 + p4, h1 = p2 + p5;
        float ox1 = (p3 - p0) * 0.5f, oy1 = (p4 - p1) * 0.5f, oz1 = (p5 - p2) * 0.5f;
        float sA = __sinf(p6), cA = __cosf(p6);
        float cx1 = ox1 * cA - oy1 * sA, cy1 = ox1 * sA + oy1 * cA;

        float w2 = q0 + q3, l2 = q1 + q4, h2 = q2 + q5;
        float ox2 = (q3 - q0) * 0.5f, oy2 = (q4 - q1) * 0.5f, oz2 = (q5 - q2) * 0.5f;
        float sB = __sinf(q6), cB = __cosf(q6);
        float cx2 = ox2 * cB - oy2 * sB, cy2 = ox2 * sB + oy2 * cB;

        // ---- corners: signs (+,+),(-,+),(-,-),(+,-) of (w/2, l/2), rotated ----
        float hw1 = 0.5f * w1, hl1 = 0.5f * l1;
        float c1x0 =  hw1 * cA - hl1 * sA + cx1, c1y0 =  hw1 * sA + hl1 * cA + cy1;
        float c1x1 = -hw1 * cA - hl1 * sA + cx1, c1y1 = -hw1 * sA + hl1 * cA + cy1;
        float c1x2 = -hw1 * cA + hl1 * sA + cx1, c1y2 = -hw1 * sA - hl1 * cA + cy1;
        float c1x3 =  hw1 * cA + hl1 * sA + cx1, c1y3 =  hw1 * sA - hl1 * cA + cy1;
        float hw2 = 0.5f * w2, hl2 = 0.5f * l2;
        float c2x0 =  hw2 * cB - hl2 * sB + cx2, c2y0 =  hw2 * sB + hl2 * cB + cy2;
        float c2x1 = -hw2 * cB - hl2 * sB + cx2, c2y1 = -hw2 * sB + hl2 * cB + cy2;
        float c2x2 = -hw2 * cB + hl2 * sB + cx2, c2y2 = -hw2 * sB - hl2 * cB + cy2;
        float c2x3 =  hw2 * cB + hl2 * sB + cx2, c2y3 =  hw2 * sB - hl2 * cB + cy2;

        float sumx = 0.0f, sumy = 0.0f;
        int nv = 0;
#define ACC(M, X, Y) { sumx += (M) ? (X) : 0.0f; sumy += (M) ? (Y) : 0.0f; nv += (M) ? 1 : 0; }

        // ---- point-in-box masks (ref: a=corner0, b=corner1, d=corner3, tol=1e-6) ----
        const float TOL = 1e-6f;
        // box1 corners in box2
        float abxB = c2x1 - c2x0, abyB = c2y1 - c2y0;
        float adxB = c2x3 - c2x0, adyB = c2y3 - c2y0;
        float rabB = RCP(abxB * abxB + abyB * abyB);
        float radB = RCP(adxB * adxB + adyB * adyB);
#define PIB_B(MX, MY, M) { float amx = (MX) - c2x0, amy = (MY) - c2y0; \
        float pab = (abxB * amx + abyB * amy) * rabB; \
        float pdd = (adxB * amx + adyB * amy) * radB; \
        M = (pab > -TOL) & (pab < 1.0f + TOL) & (pdd > -TOL) & (pdd < 1.0f + TOL); }
        bool mA0, mA1, mA2, mA3;
        PIB_B(c1x0, c1y0, mA0) PIB_B(c1x1, c1y1, mA1)
        PIB_B(c1x2, c1y2, mA2) PIB_B(c1x3, c1y3, mA3)
        ACC(mA0, c1x0, c1y0) ACC(mA1, c1x1, c1y1) ACC(mA2, c1x2, c1y2) ACC(mA3, c1x3, c1y3)
        // box2 corners in box1
        float abxA = c1x1 - c1x0, abyA = c1y1 - c1y0;
        float adxA = c1x3 - c1x0, adyA = c1y3 - c1y0;
        float rabA = RCP(abxA * abxA + abyA * abyA);
        float radA = RCP(adxA * adxA + adyA * adyA);
#define PIB_A(MX, MY, M) { float amx = (MX) - c1x0, amy = (MY) - c1y0; \
        float pab = (abxA * amx + abyA * amy) * rabA; \
        float pdd = (adxA * amx + adyA * amy) * radA; \
        M = (pab > -TOL) & (pab < 1.0f + TOL) & (pdd > -TOL) & (pdd < 1.0f + TOL); }
        bool mB0, mB1, mB2, mB3;
        PIB_A(c2x0, c2y0, mB0) PIB_A(c2x1, c2y1, mB1)
        PIB_A(c2x2, c2y2, mB2) PIB_A(c2x3, c2y3, mB3)
        ACC(mB0, c2x0, c2y0) ACC(mB1, c2x1, c2y1) ACC(mB2, c2x2, c2y2) ACC(mB3, c2x3, c2y3)

        // ---- edge-edge intersections; per box1-edge keep first 2 valid ----
        // mask from t=den_t*rcp(num), u=-den_u*rcp(num); num==0 -> inf/nan -> false
        // point uses t (ref's t2=den_t/(num+1e-8): rel diff ~1e-9, irrelevant at 2% thr)
#define ISECT(X1, Y1, X2, Y2, X3, Y3, X4, Y4, PX, PY, M) { \
        float ex = (X2) - (X1), ey = (Y2) - (Y1); \
        float fx = (X4) - (X3), fy = (Y4) - (Y3); \
        float gx = (X1) - (X3), gy = (Y1) - (Y3); \
        float num = fy * ex - fx * ey; \
        float dt_ = fx * gy - fy * gx; \
        float du_ = ex * gy - ey * gx; \
        float rr = RCP(num); \
        float tt = dt_ * rr, uu = -du_ * rr; \
        M = (tt > 0.0f) & (tt < 1.0f) & (uu > 0.0f) & (uu < 1.0f); \
        PX = (X1) + tt * ex; PY = (Y1) + tt * ey; }
#define SITEM(PX, PY, M, OX0, OY0, OX1, OY1, CNT) { \
        bool tk0 = (M) && ((CNT) == 0); bool tk1 = (M) && ((CNT) == 1); \
        OX0 = tk0 ? (PX) : OX0; OY0 = tk0 ? (PY) : OY0; \
        OX1 = tk1 ? (PX) : OX1; OY1 = tk1 ? (PY) : OY1; \
        CNT += (M) ? 1 : 0; }
#define EDGE_GROUP(X1, Y1, X2, Y2, EX0, EY0, EM0, EX1, EY1, EM1) { \
        int gc = 0; float px, py; bool mm; \
        ISECT(X1, Y1, X2, Y2, c2x0, c2y0, c2x1, c2y1, px, py, mm) \
        ACC(mm, px, py) SITEM(px, py, mm, EX0, EY0, EX1, EY1, gc) \
        ISECT(X1, Y1, X2, Y2, c2x1, c2y1, c2x2, c2y2, px, py, mm) \
        ACC(mm, px, py) SITEM(px, py, mm, EX0, EY0, EX1, EY1, gc) \
        ISECT(X1, Y1, X2, Y2, c2x2, c2y2, c2x3, c2y3, px, py, mm) \
        ACC(mm, px, py) SITEM(px, py, mm, EX0, EY0, EX1, EY1, gc) \
        ISECT(X1, Y1, X2, Y2, c2x3, c2y3, c2x0, c2y0, px, py, mm) \
        ACC(mm, px, py) SITEM(px, py, mm, EX0, EY0, EX1, EY1, gc) \
        EM0 = (gc > 0); EM1 = (gc > 1); }

        float vx8 = 0.f, vy8 = 0.f, vx9 = 0.f, vy9 = 0.f;   bool m8, m9;
        float vx10 = 0.f, vy10 = 0.f, vx11 = 0.f, vy11 = 0.f; bool m10, m11;
        float vx12 = 0.f, vy12 = 0.f, vx13 = 0.f, vy13 = 0.f; bool m12, m13;
        float vx14 = 0.f, vy14 = 0.f, vx15 = 0.f, vy15 = 0.f; bool m14, m15;
        EDGE_GROUP(c1x0, c1y0, c1x1, c1y1, vx8, vy8, m8, vx9, vy9, m9)
        EDGE_GROUP(c1x1, c1y1, c1x2, c1y2, vx10, vy10, m10, vx11, vy11, m11)
        EDGE_GROUP(c1x2, c1y2, c1x3, c1y3, vx12, vy12, m12, vx13, vy13, m13)
        EDGE_GROUP(c1x3, c1y3, c1x0, c1y0, vx14, vy14, m14, vx15, vy15, m15)

        // elements 0..7 = corners (candidate order preserved: box1 then box2)
        float vx0 = c1x0, vy0 = c1y0, vx1 = c1x1, vy1 = c1y1;
        float vx2 = c1x2, vy2 = c1y2, vx3 = c1x3, vy3 = c1y3;
        float vx4 = c2x0, vy4 = c2y0, vx5 = c2x1, vy5 = c2y1;
        float vx6 = c2x2, vy6 = c2y2, vx7 = c2x3, vy7 = c2y3;
        bool m0 = mA0, m1 = mA1, m2 = mA2, m3 = mA3;
        bool m4 = mB0, m5 = mB1, m6 = mB2, m7 = mB3;

        // ---- centroid + pseudo-angle (monotone in atan2; invalid -> 1e6) ----
        float inv_nv = RCP(fmaxf((float)nv, 1.0f));
        float mx_ = sumx * inv_nv, my_ = sumy * inv_nv;
        float ang0, ang1, ang2, ang3, ang4, ang5, ang6, ang7;
        float ang8, ang9, ang10, ang11, ang12, ang13, ang14, ang15;
#define ANG(K) { vx##K -= mx_; vy##K -= my_; \
        float dd = vy##K * RCP(fmaxf(fabsf(vx##K) + fabsf(vy##K), 1e-38f)); \
        ang##K = m##K ? ((vx##K >= 0.0f) ? dd : copysignf(2.0f, vy##K) - dd) : 1e6f; }
        ANG(0) ANG(1) ANG(2) ANG(3) ANG(4) ANG(5) ANG(6) ANG(7)
        ANG(8) ANG(9) ANG(10) ANG(11) ANG(12) ANG(13) ANG(14) ANG(15)

        // ---- odd-even transposition sort, 16 elements, 16 rounds ----
#define CE(A, B) { bool sw = ang##A > ang##B; \
        float t0 = ang##A, t1 = ang##B; ang##A = sw ? t1 : t0; ang##B = sw ? t0 : t1; \
        float u0 = vx##A, u1 = vx##B;   vx##A = sw ? u1 : u0;  vx##B = sw ? u0 : u1; \
        float w0 = vy##A, w1 = vy##B;   vy##A = sw ? w1 : w0;  vy##B = sw ? w0 : w1; }
#define ROUND_E CE(0,1) CE(2,3) CE(4,5) CE(6,7) CE(8,9) CE(10,11) CE(12,13) CE(14,15)
#define ROUND_O CE(1,2) CE(3,4) CE(5,6) CE(7,8) CE(9,10) CE(11,12) CE(13,14)
        ROUND_E ROUND_O ROUND_E ROUND_O ROUND_E ROUND_O ROUND_E ROUND_O
        ROUND_E ROUND_O ROUND_E ROUND_O ROUND_E ROUND_O ROUND_E ROUND_O

        // ---- ref padding: positions >= nv become first sorted vertex ----
#define PAD(K) { bool pd = ((K) >= nv); vx##K = pd ? vx0 : vx##K; vy##K = pd ? vy0 : vy##K; }
        PAD(1) PAD(2) PAD(3) PAD(4) PAD(5) PAD(6) PAD(7) PAD(8)
        PAD(9) PAD(10) PAD(11) PAD(12) PAD(13) PAD(14) PAD(15)

        // ---- cyclic shoelace over 16 (positions >=nv all equal v0 -> 0 terms) ----
        float cs = 0.0f;
#define SHOE(A, B) cs += vx##A * vy##B - vy##A * vx##B;
        SHOE(0,1) SHOE(1,2) SHOE(2,3) SHOE(3,4) SHOE(4,5) SHOE(5,6) SHOE(6,7) SHOE(7,8)
        SHOE(8,9) SHOE(9,10) SHOE(10,11) SHOE(11,12) SHOE(12,13) SHOE(13,14) SHOE(14,15) SHOE(15,0)
        float inter = 0.5f * fabsf(cs);

        // ---- cal_iou_3d + loss ----
        float area1 = w1 * l1, area2 = w2 * l2;
        float u2 = area1 + area2 - inter;
        float iou2d = inter / u2;
        float zmax1 = oz1 + h1 * 0.5f, zmin1 = oz1 - h1 * 0.5f;
        float zmax2 = oz2 + h2 * 0.5f, zmin2 = oz2 - h2 * 0.5f;
        float zo = fmaxf(fminf(zmax1, zmax2) - fmaxf(zmin1, zmin2), 0.0f);
        float inter3d = iou2d * u2 * zo;
        float vol1 = area1 * h1, vol2 = area2 * h2;
        float u3d = vol1 + vol2 - inter3d;
        float iouf = (inter3d + 1.0f) / (u3d + 1.0f);   // (iou3d*u3d+1)/(u3d+1)
        loss = -__logf(iouf) * wgt[i];
    }

    // ---- block reduction -> one atomicAdd per block ----
#pragma unroll
    for (int off = 32; off > 0; off >>= 1)
        loss += __shfl_down(loss, off, 64);
    __shared__ float wsum[4];
    int lane = threadIdx.x & 63, wid = threadIdx.x >> 6;
    if (lane == 0) wsum[wid] = loss;
    __syncthreads();
    if (threadIdx.x == 0) {
        float s = wsum[0] + wsum[1] + wsum[2] + wsum[3];
        atomicAdd(out, s);
    }
}

extern "C" void kernel_launch(void* const* d_in, const int* in_sizes, int n_in,
                              void* d_out, int out_size, void* d_ws, size_t ws_size,
                              hipStream_t stream) {
    const float* pred = (const float*)d_in[0];
    const float* tgt  = (const float*)d_in[1];
    const float* wgt  = (const float*)d_in[2];
    float* out = (float*)d_out;
    int n = in_sizes[2];

    hipMemsetAsync(out, 0, sizeof(float), stream);
    int block = 256;
    int grid = (n + block - 1) / block;
    riou_loss_kernel<<<grid, block, 0, stream>>>(pred, tgt, wgt, out, n);
}

// Round 5
// 81.846 us; speedup vs baseline: 1.8519x; 1.1255x over previous
//
#include <hip/hip_runtime.h>
#include <math.h>

// Rotated 3D IoU loss — round 5.
//  - All named scalars (no allocas -> nothing can be SROA-demoted).
//  - __launch_bounds__(256, 1): release allocator occupancy pressure.
//    Round-2 evidence (VGPR_Count=56 w/ 30.5MB scratch writes) showed the
//    allocator squeezing under the 8-waves/64-VGPR target by spilling;
//    live set here is ~90-150 floats -> let it take ~200 VGPRs, zero spill.
//  - Batcher odd-even mergesort over 16 (63 CEs, depth 10) by pseudo-angle.
//  - 16 candidates: 8 corners + first-2-valid crossings per box1 edge
//    (a line crosses a convex quad <=2x); candidate order preserved.
//  - Fast math: v_rcp_f32 divisions, __sinf/__cosf/__logf (2%-of-sum thr).

#define RCP(x) __builtin_amdgcn_rcpf(x)

__global__ __launch_bounds__(256, 1) void riou_loss_kernel(
    const float* __restrict__ pred, const float* __restrict__ tgt,
    const float* __restrict__ wgt, float* __restrict__ out, int n)
{
    int i = blockIdx.x * blockDim.x + threadIdx.x;
    float loss = 0.0f;
    if (i < n) {
        const float* pp = pred + 7 * i;
        const float* qq = tgt + 7 * i;
        float p0 = pp[0], p1 = pp[1], p2 = pp[2], p3 = pp[3], p4 = pp[4], p5 = pp[5], p6 = pp[6];
        float q0 = qq[0], q1 = qq[1], q2 = qq[2], q3 = qq[3], q4 = qq[4], q5 = qq[5], q6 = qq[6];

        // ---- decode_fcos_obb (loc = 0) ----
        float w1 = p0 + p3, l1 = p1 + p4, h1 = p2 + p5;
        float ox1 = (p3 - p0) * 0.5f, oy1 = (p4 - p1) * 0.5f, oz1 = (p5 - p2) * 0.5f;
        float sA = __sinf(p6), cA = __cosf(p6);
        float cx1 = ox1 * cA - oy1 * sA, cy1 = ox1 * sA + oy1 * cA;

        float w2 = q0 + q3, l2 = q1 + q4, h2 = q2 + q5;
        float ox2 = (q3 - q0) * 0.5f, oy2 = (q4 - q1) * 0.5f, oz2 = (q5 - q2) * 0.5f;
        float sB = __sinf(q6), cB = __cosf(q6);
        float cx2 = ox2 * cB - oy2 * sB, cy2 = ox2 * sB + oy2 * cB;

        // ---- corners: signs (+,+),(-,+),(-,-),(+,-) of (w/2, l/2), rotated ----
        float hw1 = 0.5f * w1, hl1 = 0.5f * l1;
        float c1x0 =  hw1 * cA - hl1 * sA + cx1, c1y0 =  hw1 * sA + hl1 * cA + cy1;
        float c1x1 = -hw1 * cA - hl1 * sA + cx1, c1y1 = -hw1 * sA + hl1 * cA + cy1;
        float c1x2 = -hw1 * cA + hl1 * sA + cx1, c1y2 = -hw1 * sA - hl1 * cA + cy1;
        float c1x3 =  hw1 * cA + hl1 * sA + cx1, c1y3 =  hw1 * sA - hl1 * cA + cy1;
        float hw2 = 0.5f * w2, hl2 = 0.5f * l2;
        float c2x0 =  hw2 * cB - hl2 * sB + cx2, c2y0 =  hw2 * sB + hl2 * cB + cy2;
        float c2x1 = -hw2 * cB - hl2 * sB + cx2, c2y1 = -hw2 * sB + hl2 * cB + cy2;
        float c2x2 = -hw2 * cB + hl2 * sB + cx2, c2y2 = -hw2 * sB - hl2 * cB + cy2;
        float c2x3 =  hw2 * cB + hl2 * sB + cx2, c2y3 =  hw2 * sB - hl2 * cB + cy2;

        float sumx = 0.0f, sumy = 0.0f;
        int nv = 0;
#define ACC(M, X, Y) { sumx += (M) ? (X) : 0.0f; sumy += (M) ? (Y) : 0.0f; nv += (M) ? 1 : 0; }

        // ---- point-in-box masks (ref: a=corner0, b=corner1, d=corner3, tol=1e-6) ----
        const float TOL = 1e-6f;
        float abxB = c2x1 - c2x0, abyB = c2y1 - c2y0;
        float adxB = c2x3 - c2x0, adyB = c2y3 - c2y0;
        float rabB = RCP(abxB * abxB + abyB * abyB);
        float radB = RCP(adxB * adxB + adyB * adyB);
#define PIB_B(MX, MY, M) { float amx = (MX) - c2x0, amy = (MY) - c2y0; \
        float pab = (abxB * amx + abyB * amy) * rabB; \
        float pdd = (adxB * amx + adyB * amy) * radB; \
        M = (pab > -TOL) & (pab < 1.0f + TOL) & (pdd > -TOL) & (pdd < 1.0f + TOL); }
        bool mA0, mA1, mA2, mA3;
        PIB_B(c1x0, c1y0, mA0) PIB_B(c1x1, c1y1, mA1)
        PIB_B(c1x2, c1y2, mA2) PIB_B(c1x3, c1y3, mA3)
        ACC(mA0, c1x0, c1y0) ACC(mA1, c1x1, c1y1) ACC(mA2, c1x2, c1y2) ACC(mA3, c1x3, c1y3)
        float abxA = c1x1 - c1x0, abyA = c1y1 - c1y0;
        float adxA = c1x3 - c1x0, adyA = c1y3 - c1y0;
        float rabA = RCP(abxA * abxA + abyA * abyA);
        float radA = RCP(adxA * adxA + adyA * adyA);
#define PIB_A(MX, MY, M) { float amx = (MX) - c1x0, amy = (MY) - c1y0; \
        float pab = (abxA * amx + abyA * amy) * rabA; \
        float pdd = (adxA * amx + adyA * amy) * radA; \
        M = (pab > -TOL) & (pab < 1.0f + TOL) & (pdd > -TOL) & (pdd < 1.0f + TOL); }
        bool mB0, mB1, mB2, mB3;
        PIB_A(c2x0, c2y0, mB0) PIB_A(c2x1, c2y1, mB1)
        PIB_A(c2x2, c2y2, mB2) PIB_A(c2x3, c2y3, mB3)
        ACC(mB0, c2x0, c2y0) ACC(mB1, c2x1, c2y1) ACC(mB2, c2x2, c2y2) ACC(mB3, c2x3, c2y3)

        // ---- edge-edge intersections; per box1-edge keep first 2 valid ----
#define ISECT(X1, Y1, X2, Y2, X3, Y3, X4, Y4, PX, PY, M) { \
        float ex = (X2) - (X1), ey = (Y2) - (Y1); \
        float fx = (X4) - (X3), fy = (Y4) - (Y3); \
        float gx = (X1) - (X3), gy = (Y1) - (Y3); \
        float num = fy * ex - fx * ey; \
        float dt_ = fx * gy - fy * gx; \
        float du_ = ex * gy - ey * gx; \
        float rr = RCP(num); \
        float tt = dt_ * rr, uu = -du_ * rr; \
        M = (tt > 0.0f) & (tt < 1.0f) & (uu > 0.0f) & (uu < 1.0f); \
        PX = (X1) + tt * ex; PY = (Y1) + tt * ey; }
#define SITEM(PX, PY, M, OX0, OY0, OX1, OY1, CNT) { \
        bool tk0 = (M) && ((CNT) == 0); bool tk1 = (M) && ((CNT) == 1); \
        OX0 = tk0 ? (PX) : OX0; OY0 = tk0 ? (PY) : OY0; \
        OX1 = tk1 ? (PX) : OX1; OY1 = tk1 ? (PY) : OY1; \
        CNT += (M) ? 1 : 0; }
#define EDGE_GROUP(X1, Y1, X2, Y2, EX0, EY0, EM0, EX1, EY1, EM1) { \
        int gc = 0; float px, py; bool mm; \
        ISECT(X1, Y1, X2, Y2, c2x0, c2y0, c2x1, c2y1, px, py, mm) \
        ACC(mm, px, py) SITEM(px, py, mm, EX0, EY0, EX1, EY1, gc) \
        ISECT(X1, Y1, X2, Y2, c2x1, c2y1, c2x2, c2y2, px, py, mm) \
        ACC(mm, px, py) SITEM(px, py, mm, EX0, EY0, EX1, EY1, gc) \
        ISECT(X1, Y1, X2, Y2, c2x2, c2y2, c2x3, c2y3, px, py, mm) \
        ACC(mm, px, py) SITEM(px, py, mm, EX0, EY0, EX1, EY1, gc) \
        ISECT(X1, Y1, X2, Y2, c2x3, c2y3, c2x0, c2y0, px, py, mm) \
        ACC(mm, px, py) SITEM(px, py, mm, EX0, EY0, EX1, EY1, gc) \
        EM0 = (gc > 0); EM1 = (gc > 1); }

        float vx8 = 0.f, vy8 = 0.f, vx9 = 0.f, vy9 = 0.f;   bool m8, m9;
        float vx10 = 0.f, vy10 = 0.f, vx11 = 0.f, vy11 = 0.f; bool m10, m11;
        float vx12 = 0.f, vy12 = 0.f, vx13 = 0.f, vy13 = 0.f; bool m12, m13;
        float vx14 = 0.f, vy14 = 0.f, vx15 = 0.f, vy15 = 0.f; bool m14, m15;
        EDGE_GROUP(c1x0, c1y0, c1x1, c1y1, vx8, vy8, m8, vx9, vy9, m9)
        EDGE_GROUP(c1x1, c1y1, c1x2, c1y2, vx10, vy10, m10, vx11, vy11, m11)
        EDGE_GROUP(c1x2, c1y2, c1x3, c1y3, vx12, vy12, m12, vx13, vy13, m13)
        EDGE_GROUP(c1x3, c1y3, c1x0, c1y0, vx14, vy14, m14, vx15, vy15, m15)

        float vx0 = c1x0, vy0 = c1y0, vx1 = c1x1, vy1 = c1y1;
        float vx2 = c1x2, vy2 = c1y2, vx3 = c1x3, vy3 = c1y3;
        float vx4 = c2x0, vy4 = c2y0, vx5 = c2x1, vy5 = c2y1;
        float vx6 = c2x2, vy6 = c2y2, vx7 = c2x3, vy7 = c2y3;
        bool m0 = mA0, m1 = mA1, m2 = mA2, m3 = mA3;
        bool m4 = mB0, m5 = mB1, m6 = mB2, m7 = mB3;

        // ---- centroid + pseudo-angle (monotone in atan2; invalid -> 1e6) ----
        float inv_nv = RCP(fmaxf((float)nv, 1.0f));
        float mx_ = sumx * inv_nv, my_ = sumy * inv_nv;
        float ang0, ang1, ang2, ang3, ang4, ang5, ang6, ang7;
        float ang8, ang9, ang10, ang11, ang12, ang13, ang14, ang15;
#define ANG(K) { vx##K -= mx_; vy##K -= my_; \
        float dd = vy##K * RCP(fmaxf(fabsf(vx##K) + fabsf(vy##K), 1e-38f)); \
        ang##K = m##K ? ((vx##K >= 0.0f) ? dd : copysignf(2.0f, vy##K) - dd) : 1e6f; }
        ANG(0) ANG(1) ANG(2) ANG(3) ANG(4) ANG(5) ANG(6) ANG(7)
        ANG(8) ANG(9) ANG(10) ANG(11) ANG(12) ANG(13) ANG(14) ANG(15)

        // ---- Batcher odd-even mergesort, 16 elements, 63 CEs, depth 10 ----
#define CE(A, B) { bool sw = ang##A > ang##B; \
        float t0 = ang##A, t1 = ang##B; ang##A = sw ? t1 : t0; ang##B = sw ? t0 : t1; \
        float u0 = vx##A, u1 = vx##B;   vx##A = sw ? u1 : u0;  vx##B = sw ? u0 : u1; \
        float w0 = vy##A, w1 = vy##B;   vy##A = sw ? w1 : w0;  vy##B = sw ? w0 : w1; }
        CE(0,1) CE(2,3) CE(4,5) CE(6,7) CE(8,9) CE(10,11) CE(12,13) CE(14,15)
        CE(0,2) CE(1,3) CE(4,6) CE(5,7) CE(8,10) CE(9,11) CE(12,14) CE(13,15)
        CE(1,2) CE(5,6) CE(9,10) CE(13,14)
        CE(0,4) CE(1,5) CE(2,6) CE(3,7) CE(8,12) CE(9,13) CE(10,14) CE(11,15)
        CE(2,4) CE(3,5) CE(10,12) CE(11,13)
        CE(1,2) CE(3,4) CE(5,6) CE(9,10) CE(11,12) CE(13,14)
        CE(0,8) CE(1,9) CE(2,10) CE(3,11) CE(4,12) CE(5,13) CE(6,14) CE(7,15)
        CE(4,8) CE(5,9) CE(6,10) CE(7,11)
        CE(2,4) CE(3,5) CE(6,8) CE(7,9) CE(10,12) CE(11,13)
        CE(1,2) CE(3,4) CE(5,6) CE(7,8) CE(9,10) CE(11,12) CE(13,14)

        // ---- ref padding: positions >= nv become first sorted vertex ----
#define PAD(K) { bool pd = ((K) >= nv); vx##K = pd ? vx0 : vx##K; vy##K = pd ? vy0 : vy##K; }
        PAD(1) PAD(2) PAD(3) PAD(4) PAD(5) PAD(6) PAD(7) PAD(8)
        PAD(9) PAD(10) PAD(11) PAD(12) PAD(13) PAD(14) PAD(15)

        // ---- cyclic shoelace over 16 ----
        float cs = 0.0f;
#define SHOE(A, B) cs += vx##A * vy##B - vy##A * vx##B;
        SHOE(0,1) SHOE(1,2) SHOE(2,3) SHOE(3,4) SHOE(4,5) SHOE(5,6) SHOE(6,7) SHOE(7,8)
        SHOE(8,9) SHOE(9,10) SHOE(10,11) SHOE(11,12) SHOE(12,13) SHOE(13,14) SHOE(14,15) SHOE(15,0)
        float inter = 0.5f * fabsf(cs);

        // ---- cal_iou_3d + loss (iou2d*u2 cancels u2 -> inter3d = inter*zo) ----
        float zmax1 = oz1 + h1 * 0.5f, zmin1 = oz1 - h1 * 0.5f;
        float zmax2 = oz2 + h2 * 0.5f, zmin2 = oz2 - h2 * 0.5f;
        float zo = fmaxf(fminf(zmax1, zmax2) - fmaxf(zmin1, zmin2), 0.0f);
        float inter3d = inter * zo;
        float vol1 = w1 * l1 * h1, vol2 = w2 * l2 * h2;
        float u3d = vol1 + vol2 - inter3d;
        float iouf = (inter3d + 1.0f) * RCP(u3d + 1.0f);
        loss = -__logf(iouf) * wgt[i];
    }

    // ---- block reduction -> one atomicAdd per block ----
#pragma unroll
    for (int off = 32; off > 0; off >>= 1)
        loss += __shfl_down(loss, off, 64);
    __shared__ float wsum[4];
    int lane = threadIdx.x & 63, wid = threadIdx.x >> 6;
    if (lane == 0) wsum[wid] = loss;
    __syncthreads();
    if (threadIdx.x == 0) {
        float s = wsum[0] + wsum[1] + wsum[2] + wsum[3];
        atomicAdd(out, s);
    }
}

extern "C" void kernel_launch(void* const* d_in, const int* in_sizes, int n_in,
                              void* d_out, int out_size, void* d_ws, size_t ws_size,
                              hipStream_t stream) {
    const float* pred = (const float*)d_in[0];
    const float* tgt  = (const float*)d_in[1];
    const float* wgt  = (const float*)d_in[2];
    float* out = (float*)d_out;
    int n = in_sizes[2];

    hipMemsetAsync(out, 0, sizeof(float), stream);
    int block = 256;
    int grid = (n + block - 1) / block;
    riou_loss_kernel<<<grid, block, 0, stream>>>(pred, tgt, wgt, out, n);
}